// Round 6
// baseline (287.690 us; speedup 1.0000x reference)
//
#include <hip/hip_runtime.h>

// DetectionLayer decode, fp32, N=2M rows x C=85 cols.
// out[r][0:2] = in[r][0:2]*an[r][2:4] + an[r][0:2]
// out[r][2:4] = exp(in[r][2:4])*an[r][2:4]
// out[r][4:]  = in[r][4:]   ; row zeroed when in[r][5] <= 0.5
//
// Round-6 structure: persistent blocks + register-staged pipeline.
// R5 evidence: 250 us but actual HBM only ~4.26 TB/s (68%) with nothing
// saturated -> bursty load/store phases (blocks phase-locked per CU).
// Here each block loops over chunks (32 rows = 680 float4), prefetching the
// NEXT chunk into registers before the masked store of the current chunk, so
// loads are always in flight under the store phase. Decode is inlined into
// the store pass (no LDS write-back phase); anchors come from a prefetched
// LDS cache; cond is read from the raw staged row (col 5 is passthrough).
// ROWS=32 -> 11.4 KB LDS; launch_bounds(256,8) -> 8 blocks/CU = 32 waves/CU.

typedef float f4 __attribute__((ext_vector_type(4)));

#define DET_C   85u
#define ROWS    32u
#define CH_ELEM (DET_C * ROWS)      // 2720 floats per chunk
#define CH_F4   (CH_ELEM / 4u)      // 680 float4 per chunk (= 2*256 + 168)
#define NBLK    2048u

__global__ __launch_bounds__(256, 8) void DetectionLayer_kernel(
    const float* __restrict__ in,       // [N*85]
    const float* __restrict__ anchors,  // [N*4]
    float* __restrict__ out,            // [N*85]
    unsigned int N)
{
    __shared__ f4 lds4[CH_F4];
    __shared__ f4 an_cache[ROWS];
    float* ldsf = (float*)lds4;

    const unsigned int tid = threadIdx.x;
    const unsigned int G   = gridDim.x;
    const unsigned int nch = N / ROWS;            // full 32-row chunks

    const unsigned int i0 = tid;
    const unsigned int i1 = tid + 256u;
    const unsigned int i2 = tid + 512u;
    const bool has2 = (i2 < CH_F4);               // tid < 168

    const f4* in4  = (const f4*)in;
    const f4* anc4 = (const f4*)anchors;
    f4*       out4 = (f4*)out;

    unsigned int c = blockIdx.x;
    f4 r0, r1, r2, anR;

    // prologue prefetch
    if (c < nch) {
        const f4* p = in4 + (size_t)c * CH_F4;
        r0 = p[i0];
        r1 = p[i1];
        if (has2) r2 = p[i2];
        if (tid < ROWS) anR = anc4[(size_t)c * ROWS + tid];
    }

    while (c < nch) {
        __syncthreads();                          // LDS free (prev stores done)
        lds4[i0] = r0;
        lds4[i1] = r1;
        if (has2) lds4[i2] = r2;
        if (tid < ROWS) an_cache[tid] = anR;
        __syncthreads();                          // LDS ready

        // prefetch next chunk into registers — in flight under the stores below
        const unsigned int cn = c + G;
        if (cn < nch) {
            const f4* p = in4 + (size_t)cn * CH_F4;
            r0 = p[i0];
            r1 = p[i1];
            if (has2) r2 = p[i2];
            if (tid < ROWS) anR = anc4[(size_t)cn * ROWS + tid];
        }

        // decode + mask + nt-store chunk c from LDS
        f4* ob = out4 + (size_t)c * CH_F4;
#pragma unroll
        for (int k = 0; k < 3; ++k) {
            if (k == 2 && !has2) break;
            const unsigned int i = (k == 0) ? i0 : (k == 1) ? i1 : i2;
            f4 v = lds4[i];
            const unsigned int e0 = i * 4u;
            const unsigned int rl = e0 / DET_C;   // const 85 -> magic mul
            const unsigned int c0 = e0 - rl * DET_C;
            if (c0 >= 4u && c0 <= DET_C - 4u) {
                // pure passthrough, single row
                const float m = ldsf[rl * DET_C + 5u] > 0.5f ? 1.0f : 0.0f;
                v.x *= m; v.y *= m; v.z *= m; v.w *= m;
            } else {
                float vv[4] = {v.x, v.y, v.z, v.w};
#pragma unroll
                for (int j = 0; j < 4; ++j) {
                    unsigned int cc = c0 + (unsigned int)j;
                    unsigned int rr = rl;
                    if (cc >= DET_C) { cc -= DET_C; ++rr; }   // stays in chunk
                    float d = vv[j];
                    if (cc < 4u) {
                        const f4 an = an_cache[rr];
                        if (cc == 0u)      d = d * an.z + an.x;       // pred_y
                        else if (cc == 1u) d = d * an.w + an.y;       // pred_x
                        else if (cc == 2u) d = __expf(d) * an.z;      // pred_h
                        else               d = __expf(d) * an.w;      // pred_w
                    }
                    const float m = ldsf[rr * DET_C + 5u] > 0.5f ? 1.0f : 0.0f;
                    vv[j] = d * m;
                }
                v.x = vv[0]; v.y = vv[1]; v.z = vv[2]; v.w = vv[3];
            }
            __builtin_nontemporal_store(v, &ob[i]);
        }
        c = cn;
    }

    // leftover rows (N % 32 != 0) — scalar grid-stride; not hit for N=2M
    const size_t e_start = (size_t)nch * CH_ELEM;
    const size_t n_elem  = (size_t)N * DET_C;
    for (size_t e = e_start + (size_t)blockIdx.x * 256u + tid; e < n_elem;
         e += (size_t)G * 256u) {
        const size_t rg = e / DET_C;
        const unsigned int cc = (unsigned int)(e - rg * DET_C);
        const float condf = in[rg * DET_C + 5u] > 0.5f ? 1.0f : 0.0f;
        const float val = in[e];
        const float* ap = anchors + rg * 4u;
        float dec;
        if (cc < 2u)      dec = val * ap[2u + cc] + ap[cc];
        else if (cc < 4u) dec = __expf(val) * ap[cc];
        else              dec = val;
        __builtin_nontemporal_store(dec * condf, &out[e]);
    }
}

extern "C" void kernel_launch(void* const* d_in, const int* in_sizes, int n_in,
                              void* d_out, int out_size, void* d_ws, size_t ws_size,
                              hipStream_t stream) {
    const float* in      = (const float*)d_in[0];   // [N, 85] fp32
    const float* anchors = (const float*)d_in[1];   // [N, 4]  fp32
    float* out = (float*)d_out;

    const unsigned int N   = (unsigned int)(in_sizes[0] / 85); // 2,000,000
    const unsigned int nch = N / ROWS;                          // 62,500
    unsigned int grid = nch < NBLK ? (nch ? nch : 1u) : NBLK;   // 2048

    DetectionLayer_kernel<<<grid, 256, 0, stream>>>(in, anchors, out, N);
}

// Round 7
// 249.029 us; speedup vs baseline: 1.1552x; 1.1552x over previous
//
#include <hip/hip_runtime.h>

// DetectionLayer decode, fp32, N=2M rows x C=85 cols.
// out[r][0:2] = in[r][0:2]*an[r][2:4] + an[r][0:2]
// out[r][2:4] = exp(in[r][2:4])*an[r][2:4]
// out[r][4:]  = in[r][4:]   ; row zeroed when in[r][5] <= 0.5
//
// FINAL (round-7 = revert to round-5 best):
//   R1 flat float4:        434 us (latency-bound, VGPR=12, divergent exp)
//   R2 branch-light flat:  514 us (still 1 load in flight)
//   R3 row-per-thread:     460 us (write amplification 1.46x: 340B-stride
//                                  4B-aligned stores -> partial-line RMW)
//   R4 LDS-staged 64-row:  255 us (clean coalesced streams both directions)
//   R5 + nt stores:        250 us = 88.6% of the 6.29 TB/s copy ceiling
//   R6 persistent pipeline: 288 us (T14-null on streaming confirmed; fewer
//                                  blocks + more barriers/byte = regression)
// Floor arithmetic: 1.392 GB logical / 6.29 TB/s = 221 us. Remaining gap is
// mixed-stream + mask overhead; no counter shows a saturated fixable resource.

typedef float f4 __attribute__((ext_vector_type(4)));

#define DET_C   85u
#define ROWS    64u                  // rows per block
#define ELEMS   (DET_C * ROWS)       // 5440 floats per block
#define NF4     (ELEMS / 4u)         // 1360 float4 per block (= 5*256 + 80)

__global__ __launch_bounds__(256) void DetectionLayer_kernel(
    const float* __restrict__ in,       // [N*85]
    const float* __restrict__ anchors,  // [N*4]
    float* __restrict__ out,            // [N*85]
    unsigned int N)
{
    __shared__ f4 lds4[NF4];
    __shared__ float cf[ROWS];
    float* ldsf = (float*)lds4;

    const unsigned int tid  = threadIdx.x;
    const unsigned int row0 = blockIdx.x * ROWS;
    const unsigned int nrows = (N - row0 < ROWS) ? (N - row0) : ROWS;

    const size_t ebase = (size_t)row0 * DET_C;          // element base, *4B is 16B-aligned
    const f4* in4  = (const f4*)(in  + ebase);
    f4*       out4 = (f4*)(out + ebase);

    if (nrows == ROWS) {
        // ---- full block fast path ----
        // anchors: one coalesced float4 per row-owner lane, issued early
        f4 an;
        if (tid < ROWS)
            an = *(const f4*)(anchors + (size_t)(row0 + tid) * 4u);

        // phase 1: stage 64 rows, flat coalesced float4 (6 indep loads/thread)
#pragma unroll
        for (unsigned int k = 0; k < 5; ++k)
            lds4[tid + k * 256u] = in4[tid + k * 256u];
        if (tid < NF4 - 5u * 256u)                       // tid < 80
            lds4[tid + 1280u] = in4[tid + 1280u];
        __syncthreads();

        // phase 2: decode cols 0..3 in LDS, publish cond per row
        if (tid < ROWS) {
            const unsigned int o = tid * DET_C;
            const float x0 = ldsf[o + 0], x1 = ldsf[o + 1];
            const float x2 = ldsf[o + 2], x3 = ldsf[o + 3];
            cf[tid] = ldsf[o + 5] > 0.5f ? 1.0f : 0.0f;
            ldsf[o + 0] = x0 * an.z + an.x;              // pred_y
            ldsf[o + 1] = x1 * an.w + an.y;              // pred_x
            ldsf[o + 2] = __expf(x2) * an.z;             // pred_h
            ldsf[o + 3] = __expf(x3) * an.w;             // pred_w
        }
        __syncthreads();

        // phase 3: masked flat write-out, full-line coalesced, non-temporal
#pragma unroll
        for (unsigned int k = 0; k < 6; ++k) {
            const unsigned int i = tid + k * 256u;
            if (k == 5 && i >= NF4) break;
            f4 v = lds4[i];
            const unsigned int e0 = i * 4u;
            const unsigned int rl = e0 / DET_C;          // const 85 -> magic mul
            const unsigned int c0 = e0 - rl * DET_C;
            const float m0 = cf[rl];
            // at most one row crossing inside a float4
            v.x *= m0;
            v.y *= (c0 + 1u >= DET_C) ? cf[rl + 1u] : m0;
            v.z *= (c0 + 2u >= DET_C) ? cf[rl + 1u] : m0;
            v.w *= (c0 + 3u >= DET_C) ? cf[rl + 1u] : m0;
            __builtin_nontemporal_store(v, &out4[i]);
        }
    } else {
        // ---- partial tail block (never hit for N=2M; kept for safety) ----
        const unsigned int nelem = nrows * DET_C;
        for (unsigned int e = tid; e < nelem; e += 256u) {
            const unsigned int rl = e / DET_C;
            const unsigned int cc = e - rl * DET_C;
            const size_t grow = (size_t)(row0 + rl);
            const float condf = in[grow * DET_C + 5u] > 0.5f ? 1.0f : 0.0f;
            const float val = in[ebase + e];
            const float* ap = anchors + grow * 4u;
            float dec;
            if (cc < 2u)      dec = val * ap[2u + cc] + ap[cc];
            else if (cc < 4u) dec = __expf(val) * ap[cc];
            else              dec = val;
            __builtin_nontemporal_store(dec * condf, &out[ebase + e]);
        }
    }
}

extern "C" void kernel_launch(void* const* d_in, const int* in_sizes, int n_in,
                              void* d_out, int out_size, void* d_ws, size_t ws_size,
                              hipStream_t stream) {
    const float* in      = (const float*)d_in[0];   // [N, 85] fp32
    const float* anchors = (const float*)d_in[1];   // [N, 4]  fp32
    float* out = (float*)d_out;

    const unsigned int N = (unsigned int)(in_sizes[0] / 85);  // 2,000,000
    const unsigned int grid = (N + ROWS - 1) / ROWS;          // 31250 blocks

    DetectionLayer_kernel<<<grid, 256, 0, stream>>>(in, anchors, out, N);
}